// Round 4
// baseline (29.017 us; speedup 1.0000x reference)
//
#include <hip/hip_runtime.h>
#include <hip/hip_bf16.h>

// RGCN fused: out = relu( [x | agg_r0..agg_r15] @ [w_self | w_rel]^T )
// B=4096, S=10, R=16, F=128, K_total=2176.
// v4: grid = 256 m-tiles x 2 k-halves = 512 blocks (2 resident/CU) while W2
// L2 traffic stays 143 MB (each block reads only its k-half). BT=16 -> full
// 16-row MFMA tiles. Partials (f32, no relu) to d_ws; finish_relu sums+relu.

#define BT      16
#define LDA2    1160           // bf16 elems per A_t row (1152 max + 8 pad)
#define NTHR    512
#define P_OFF   (1 << 20)      // partials byte offset in d_ws
#define P_HALF  (4096 * 128)   // floats per k-half partial

typedef __attribute__((ext_vector_type(8))) short short8;  // 8 bf16
typedef __attribute__((ext_vector_type(4))) float f32x4;   // MFMA acc

__device__ __forceinline__ unsigned int pk2_rne(float lo, float hi) {
  unsigned int r;
  asm("v_cvt_pk_bf16_f32 %0, %1, %2" : "=v"(r) : "v"(lo), "v"(hi));
  return r;
}

// ---- prep: W (fp32) -> bf16 fragments, layout [ks][ot][lane], 16B/lane ----
__global__ __launch_bounds__(256)
void wprep(const float* __restrict__ w_self, const float* __restrict__ w_rel,
           uint4* __restrict__ w2)
{
  const int u  = blockIdx.x * 4 + (threadIdx.x >> 6);   // 0..543
  const int l  = threadIdx.x & 63;
  const int ln = l & 15, lj = l >> 4;
  const int ks = u >> 3, ot = u & 7;
  const int o  = ot * 16 + ln;
  const int k0 = ks * 32 + lj * 8;
  const float* src;
  if (k0 < 128) src = w_self + o * 128 + k0;
  else {
    const int r = (k0 - 128) >> 7, kc = (k0 - 128) & 127;
    src = w_rel + ((size_t)(r * 128 + o)) * 128 + kc;
  }
  const float4 a = *(const float4*)src;
  const float4 b = *(const float4*)(src + 4);
  uint4 v;
  v.x = pk2_rne(a.x, a.y); v.y = pk2_rne(a.z, a.w);
  v.z = pk2_rne(b.x, b.y); v.w = pk2_rne(b.z, b.w);
  w2[u * 64 + l] = v;
}

// ---- main: one (m-tile, k-half) per block ----
// k-half 0: units {self, rel0..rel7} = k 0..1151  (36 k-steps, global ks 0..35)
// k-half 1: units {rel8..rel15}      = k 1152..2175 (32 k-steps, global ks 36..67)
__global__ __launch_bounds__(NTHR, 4)
void rgcn_main(const float* __restrict__ emb,
               const int*   __restrict__ nodes,
               const int*   __restrict__ neighbors,
               const int*   __restrict__ rel_mask,
               const uint4* __restrict__ w2,
               float*       __restrict__ pout)
{
  __shared__ alignas(16) char smem[72704];
  // [0, 67584): union { A_t [16][1160] bf16 (37,120 B) | P [8][16][132] f32 }
  // [67584, 72704): mscale [16][10][8] f32
  unsigned short* A_t = (unsigned short*)smem;
  float* P = (float*)smem;
  float (*mscale)[10][8] = (float (*)[10][8])(smem + 67584);

  const int t  = threadIdx.x;
  const int l  = t & 63;
  const int w  = t >> 6;
  const int mt = blockIdx.x >> 1;
  const int kh = blockIdx.x & 1;
  const int b0 = mt * BT;
  const int rbase = kh * 8;
  const int ksg0  = kh ? 36 : 0;

  // ---------- mscale for this half's 8 relations ----------
  if (t < 128) {
    const int bi = t >> 3, r8 = t & 7;
    const int* mp = rel_mask + (size_t)(b0 + bi) * 160 + rbase + r8;
    int mb[10]; int c = 0;
    #pragma unroll
    for (int s = 0; s < 10; ++s) { mb[s] = mp[s * 16]; c += mb[s]; }
    const float inv = 1.0f / ((float)c + 1e-10f);
    #pragma unroll
    for (int s = 0; s < 10; ++s) mscale[bi][s][r8] = mb[s] ? inv : 0.0f;
  }
  __syncthreads();

  // ---------- Phase A: 8 waves x 2 nodes; masked means (+ self if kh==0) ----------
  {
    const int f0 = l * 2;
    #pragma unroll
    for (int nn = 0; nn < 2; ++nn) {
      const int bi = w * 2 + nn;
      const int b  = b0 + bi;
      int nb[10];
      #pragma unroll
      for (int s = 0; s < 10; ++s) nb[s] = neighbors[b * 10 + s];
      float2 ne[10];
      #pragma unroll
      for (int s = 0; s < 10; ++s)
        ne[s] = *(const float2*)(emb + (size_t)nb[s] * 128 + f0);
      char* arow = (char*)A_t + bi * (LDA2 * 2);
      if (kh == 0) {
        const int node = nodes[b];
        const float2 x2 = *(const float2*)(emb + (size_t)node * 128 + f0);
        *(unsigned int*)(arow + f0 * 2) = pk2_rne(x2.x, x2.y);   // self, k-local [0,128)
      }
      float acc[8][2];
      #pragma unroll
      for (int r = 0; r < 8; ++r) { acc[r][0] = 0.f; acc[r][1] = 0.f; }
      #pragma unroll
      for (int s = 0; s < 10; ++s) {
        const float4 m0 = *(const float4*)(&mscale[bi][s][0]);
        const float4 m1 = *(const float4*)(&mscale[bi][s][4]);
        const float m[8] = {m0.x, m0.y, m0.z, m0.w, m1.x, m1.y, m1.z, m1.w};
        const float2 v = ne[s];
        #pragma unroll
        for (int r = 0; r < 8; ++r) {
          acc[r][0] += m[r] * v.x;
          acc[r][1] += m[r] * v.y;
        }
      }
      const int rel0_off = kh ? 0 : 256;     // byte offset of first relation block
      #pragma unroll
      for (int r = 0; r < 8; ++r)
        *(unsigned int*)(arow + rel0_off + r * 256 + f0 * 2) = pk2_rne(acc[r][0], acc[r][1]);
    }
  }
  __syncthreads();

  // ---------- Phase B: k-split GEMM over this half's k-steps ----------
  const int ln = l & 15, lj = l >> 4;
  f32x4 acc[8];
  #pragma unroll
  for (int ot = 0; ot < 8; ++ot) acc[ot] = (f32x4){0.f, 0.f, 0.f, 0.f};
  {
    int ksb, kse;
    if (kh == 0) { ksb = (w < 4) ? w * 5 : 20 + (w - 4) * 4; kse = ksb + ((w < 4) ? 5 : 4); }
    else         { ksb = w * 4;                               kse = ksb + 4; }
    const char* arow = (const char*)A_t + ln * (LDA2 * 2);
    const uint4* w2p = w2 + (size_t)(ksg0 + ksb) * 8 * 64 + l;
    for (int ks = ksb; ks < kse; ++ks, w2p += 512) {
      const short8 a = *(const short8*)(arow + ks * 64 + lj * 16);
      #pragma unroll
      for (int ot = 0; ot < 8; ++ot) {
        union { uint4 u; short8 s; } wv;
        wv.u = w2p[ot * 64];
        acc[ot] = __builtin_amdgcn_mfma_f32_16x16x32_bf16(a, wv.s, acc[ot], 0, 0, 0);
      }
    }
  }
  __syncthreads();                           // A_t dead; P aliases it

  // ---------- Phase C: per-k-group partials to LDS ----------
  #pragma unroll
  for (int ot = 0; ot < 8; ++ot) {
    const int o = ot * 16 + ln;
    #pragma unroll
    for (int j = 0; j < 4; ++j)
      P[(w * 16 + lj * 4 + j) * 132 + o] = acc[ot][j];
  }
  __syncthreads();

  // ---------- Phase D: 8-way reduce -> raw f32 partial (no relu) ----------
  {
    const int row = t >> 5, o0 = (t & 31) * 4;
    f32x4 s = {0.f, 0.f, 0.f, 0.f};
    #pragma unroll
    for (int g = 0; g < 8; ++g)
      s += *(const f32x4*)(P + (g * 16 + row) * 132 + o0);
    float4 o4; o4.x = s[0]; o4.y = s[1]; o4.z = s[2]; o4.w = s[3];
    *(float4*)(pout + (size_t)kh * P_HALF + (size_t)(b0 + row) * 128 + o0) = o4;
  }
}

// ---- finish: out = relu(p0 + p1) ----
__global__ __launch_bounds__(256)
void finish_relu(const float* __restrict__ p, float* __restrict__ out) {
  const int i = (blockIdx.x * 256 + threadIdx.x) * 4;
  const float4 a = *(const float4*)(p + i);
  const float4 b = *(const float4*)(p + P_HALF + i);
  float4 o;
  o.x = fmaxf(a.x + b.x, 0.f);
  o.y = fmaxf(a.y + b.y, 0.f);
  o.z = fmaxf(a.z + b.z, 0.f);
  o.w = fmaxf(a.w + b.w, 0.f);
  *(float4*)(out + i) = o;
}

extern "C" void kernel_launch(void* const* d_in, const int* in_sizes, int n_in,
                              void* d_out, int out_size, void* d_ws, size_t ws_size,
                              hipStream_t stream) {
  const float* emb       = (const float*)d_in[0];
  const float* w_self    = (const float*)d_in[1];
  const float* w_rel     = (const float*)d_in[2];
  const int*   nodes     = (const int*)d_in[3];
  const int*   neighbors = (const int*)d_in[4];
  const int*   rel_mask  = (const int*)d_in[5];
  float* out = (float*)d_out;
  (void)in_sizes; (void)n_in; (void)out_size; (void)ws_size;

  char* ws = (char*)d_ws;
  uint4* w2   = (uint4*)ws;
  float* pout = (float*)(ws + P_OFF);

  wprep<<<136, 256, 0, stream>>>(w_self, w_rel, w2);
  rgcn_main<<<512, NTHR, 0, stream>>>(emb, nodes, neighbors, rel_mask, w2, pout);
  finish_relu<<<512, 256, 0, stream>>>(pout, out);
}